// Round 8
// baseline (132.410 us; speedup 1.0000x reference)
//
#include <hip/hip_runtime.h>
#include <math.h>

static constexpr int M = 4096;   // batch rows
static constexpr int C = 512;    // classes
static constexpr int D = 128;    // feature dim
static constexpr float ALPHA = 0.5f;

// ---------------- workspace layout (bytes) ----------------
// zero region (cleared by k_zero each call):
//   cnt      : float[C]     @ 0      (2048)
//   tile_cnt : uint[64]     @ 2048   (256)
//   sumx     : float[C*D]   @ 2304   (262144)   -> zero span [0, 264448)
// plain-stored (no init):
//   label    : int[M]       @ 264448 (16384)
//   d_pos    : float[M]     @ 280832 (16384)
//   loss_part: float[M*8]   @ 297216 (131072)
static constexpr size_t WS_CNT    = 0;
static constexpr size_t WS_TCNT   = 2048;
static constexpr size_t WS_SUMX   = 2304;
static constexpr int    ZERO_WORDS = 264448 / 4;   // 66112
static constexpr size_t WS_LABEL  = 264448;
static constexpr size_t WS_DPOS   = 280832;
static constexpr size_t WS_LPART  = 297216;

// ---- kernel 0: zero the accumulator span (replaces hipMemsetAsync) ----
__global__ __launch_bounds__(256) void k_zero(unsigned int* __restrict__ ws)
{
    int idx = blockIdx.x * 256 + threadIdx.x;
    if (idx < ZERO_WORDS) ws[idx] = 0u;
}

// ---- kernel 1: per-row argmax + scatter row into cnt/sumx (R1 pattern) ----
// one wave per row; 4 rows per 256-thread block.
__global__ __launch_bounds__(256) void k_label(
    const float* __restrict__ onehot, const float* __restrict__ x0,
    int* __restrict__ label, float* __restrict__ cnt, float* __restrict__ sumx)
{
    int gtid = blockIdx.x * 256 + threadIdx.x;
    int row  = gtid >> 6;            // grid = M/4 -> row < M always
    int lane = threadIdx.x & 63;

    const float4* oh = reinterpret_cast<const float4*>(onehot + (size_t)row * C);
    float4 a = oh[lane * 2 + 0];
    float4 b = oh[lane * 2 + 1];
    int lbl = -1;
    if (a.x > 0.5f) lbl = lane * 8 + 0;
    if (a.y > 0.5f) lbl = lane * 8 + 1;
    if (a.z > 0.5f) lbl = lane * 8 + 2;
    if (a.w > 0.5f) lbl = lane * 8 + 3;
    if (b.x > 0.5f) lbl = lane * 8 + 4;
    if (b.y > 0.5f) lbl = lane * 8 + 5;
    if (b.z > 0.5f) lbl = lane * 8 + 6;
    if (b.w > 0.5f) lbl = lane * 8 + 7;
    #pragma unroll
    for (int off = 32; off > 0; off >>= 1)
        lbl = max(lbl, __shfl_xor(lbl, off));

    if (lane == 0) {
        label[row] = lbl;
        atomicAdd(&cnt[lbl], 1.0f);
    }
    // scatter this row of x0 (wave-coalesced; avg M/C=8 colliders per cell)
    float2 xv = reinterpret_cast<const float2*>(x0 + (size_t)row * D)[lane];
    atomicAdd(&sumx[lbl * D + lane * 2 + 0], xv.x);
    atomicAdd(&sumx[lbl * D + lane * 2 + 1], xv.y);
}

// ---- kernel 2: {new_centers row b} + {L1-distance tile (mb,cb)} +
//      {last-block-per-m-tile loss finalize} ----
// grid = 512 blocks x 256 threads, 32 KB LDS (2+ blocks/CU).
__global__ __launch_bounds__(256) void k_dist(
    const float* __restrict__ x0, const float* __restrict__ centers,
    const int* __restrict__ label,
    const float* __restrict__ cnt, const float* __restrict__ sumx,
    unsigned int* __restrict__ tile_cnt,
    float* __restrict__ d_pos, float* __restrict__ loss_part,
    float* __restrict__ out_nc, float* __restrict__ loss_out)
{
    __shared__ float xs[64 * 64];    // 16 KB
    __shared__ float cs[64 * 64];    // 16 KB

    int tid = threadIdx.x;
    int b   = blockIdx.x;

    // ===== prologue: new_centers for class b (cnt/sumx are L2-hot) =====
    if (tid < D) {
        float n   = cnt[b];
        float s   = sumx[b * D + tid];
        float ctr = centers[b * D + tid];
        out_nc[b * D + tid] = ctr - ALPHA * (n * ctr - s) / (n + 1.0f);
    }

    // ===== L1-distance tile: swizzled staging (R5-proven) =====
    int mb = b & 63;            // m tile
    int cb = b >> 6;            // c chunk
    int m0 = mb * 64, c0 = cb * 64;
    int tx = tid & 15;          // -> 4 c rows
    int ty = tid >> 4;          // -> 4 m rows
    int xk = ty & 7;            // read-swizzle key for x rows
    int ck = tx & 7;            // read-swizzle key for c rows

    float acc[4][4];
    #pragma unroll
    for (int i = 0; i < 4; i++)
        #pragma unroll
        for (int j = 0; j < 4; j++) acc[i][j] = 0.f;

    for (int dc = 0; dc < 2; ++dc) {
        int d0 = dc * 64;
        __syncthreads();   // protect LDS from previous iteration's readers
        #pragma unroll
        for (int kk = 0; kk < 4; ++kk) {
            int Q   = kk * 256 + tid;                // physical quad 0..1023
            int row = Q >> 4;                        // 0..63
            int q   = (Q & 15) ^ ((row >> 2) & 7);   // logical quad (pre-swizzle
            float4 vx = *reinterpret_cast<const float4*>(   // the GLOBAL addr)
                x0      + (size_t)(m0 + row) * D + d0 + q * 4);
            float4 vc = *reinterpret_cast<const float4*>(
                centers + (size_t)(c0 + row) * D + d0 + q * 4);
            *reinterpret_cast<float4*>(xs + Q * 4) = vx;   // linear: no conflict
            *reinterpret_cast<float4*>(cs + Q * 4) = vc;
        }
        __syncthreads();

        #pragma unroll 4
        for (int q = 0; q < 16; ++q) {
            int xo = (q ^ xk) << 2;
            int co = (q ^ ck) << 2;
            float4 xa[4], ca[4];
            #pragma unroll
            for (int i = 0; i < 4; ++i)
                xa[i] = *reinterpret_cast<const float4*>(xs + (ty * 4 + i) * 64 + xo);
            #pragma unroll
            for (int j = 0; j < 4; ++j)
                ca[j] = *reinterpret_cast<const float4*>(cs + (tx * 4 + j) * 64 + co);
            #pragma unroll
            for (int i = 0; i < 4; ++i)
                #pragma unroll
                for (int j = 0; j < 4; ++j) {
                    acc[i][j] += fabsf(xa[i].x - ca[j].x);   // v_sub+v_add(|mod|)
                    acc[i][j] += fabsf(xa[i].y - ca[j].y);
                    acc[i][j] += fabsf(xa[i].z - ca[j].z);
                    acc[i][j] += fabsf(xa[i].w - ca[j].w);
                }
        }
    }

    // ===== epilogue: d_pos (unique owner) + per-chunk exp-sum partials =====
    {
        int lbls[4];
        #pragma unroll
        for (int i = 0; i < 4; i++) lbls[i] = label[m0 + ty * 4 + i];

        #pragma unroll
        for (int i = 0; i < 4; i++) {
            float ps = 0.f;
            #pragma unroll
            for (int j = 0; j < 4; j++) {
                int cg = c0 + tx * 4 + j;
                float dist = acc[i][j];
                if (cg == lbls[i]) {
                    d_pos[m0 + ty * 4 + i] = dist;        // unique writer per m
                } else {
                    ps += __expf(-dist);
                }
            }
            #pragma unroll
            for (int off = 8; off > 0; off >>= 1)         // 16-lane tx group
                ps += __shfl_xor(ps, off);
            if (tx == 0)
                loss_part[(size_t)(m0 + ty * 4 + i) * 8 + cb] = ps;
        }
    }

    // ===== last block of this m-tile finalizes its 64 losses =====
    __threadfence();             // release: stores above visible device-wide
    __syncthreads();
    int* flag = reinterpret_cast<int*>(xs);   // xs dead after compute
    if (tid == 0) {
        unsigned int old = atomicAdd(&tile_cnt[mb], 1u);
        *flag = (old == 7u) ? 1 : 0;
    }
    __syncthreads();
    if (*flag && tid < 64) {
        __threadfence();         // acquire: see other blocks' stores
        int m = m0 + tid;
        float dp = __hip_atomic_load(&d_pos[m], __ATOMIC_RELAXED,
                                     __HIP_MEMORY_SCOPE_AGENT);
        float S = 0.f;
        #pragma unroll
        for (int k = 0; k < 8; ++k)
            S += __hip_atomic_load(&loss_part[(size_t)m * 8 + k],
                                   __ATOMIC_RELAXED, __HIP_MEMORY_SCOPE_AGENT);
        loss_out[m] = dp + log1pf(S);
    }
}

extern "C" void kernel_launch(void* const* d_in, const int* in_sizes, int n_in,
                              void* d_out, int out_size, void* d_ws, size_t ws_size,
                              hipStream_t stream)
{
    const float* x0      = (const float*)d_in[0];   // (M, D)
    const float* onehot  = (const float*)d_in[1];   // (M, C)
    const float* centers = (const float*)d_in[2];   // (C, D)
    float* out = (float*)d_out;                     // [0..M) loss, [M..) new_centers

    char* ws = (char*)d_ws;
    float*        cnt       = (float*)        (ws + WS_CNT);
    unsigned int* tile_cnt  = (unsigned int*) (ws + WS_TCNT);
    float*        sumx      = (float*)        (ws + WS_SUMX);
    int*          label     = (int*)          (ws + WS_LABEL);
    float*        d_pos     = (float*)        (ws + WS_DPOS);
    float*        loss_part = (float*)        (ws + WS_LPART);

    k_zero <<<(ZERO_WORDS + 255) / 256, 256, 0, stream>>>((unsigned int*)d_ws);
    k_label<<<M / 4, 256, 0, stream>>>(onehot, x0, label, cnt, sumx);
    k_dist <<<512,   256, 0, stream>>>(x0, centers, label, cnt, sumx, tile_cnt,
                                       d_pos, loss_part, out + M, out);
}

// Round 9
// 93.867 us; speedup vs baseline: 1.4106x; 1.4106x over previous
//
#include <hip/hip_runtime.h>
#include <math.h>

static constexpr int M = 4096;   // batch rows
static constexpr int C = 512;    // classes
static constexpr int D = 128;    // feature dim
static constexpr float ALPHA = 0.5f;

// ---------------- workspace layout (bytes) ----------------
// zero region (cleared by k_zero each call):
//   cnt      : float[C]     @ 0      (2048)
//   sumx     : float[C*D]   @ 2048   (262144)  -> zero span [0, 264192)
// plain-stored (no init):
//   label    : int[M]       @ 264192 (16384)
//   d_pos    : float[M]     @ 280576 (16384)
//   loss_part: float[M*8]   @ 296960 (131072)
static constexpr size_t WS_CNT     = 0;
static constexpr size_t WS_SUMX    = 2048;
static constexpr int    ZERO_WORDS = 264192 / 4;   // 66048
static constexpr size_t WS_LABEL   = 264192;
static constexpr size_t WS_DPOS    = 280576;
static constexpr size_t WS_LPART   = 296960;

// ---- kernel 0: zero the scatter accumulators (graph-safe, ~2 us) ----
__global__ __launch_bounds__(256) void k_zero(unsigned int* __restrict__ ws)
{
    int idx = blockIdx.x * 256 + threadIdx.x;
    if (idx < ZERO_WORDS) ws[idx] = 0u;
}

// ---- kernel 1: per-row argmax + scatter row into cnt/sumx ----
// one wave per row; 4 rows per 256-thread block.
__global__ __launch_bounds__(256) void k_label(
    const float* __restrict__ onehot, const float* __restrict__ x0,
    int* __restrict__ label, float* __restrict__ cnt, float* __restrict__ sumx)
{
    int gtid = blockIdx.x * 256 + threadIdx.x;
    int row  = gtid >> 6;            // grid = M/4 -> row < M always
    int lane = threadIdx.x & 63;

    const float4* oh = reinterpret_cast<const float4*>(onehot + (size_t)row * C);
    float4 a = oh[lane * 2 + 0];
    float4 b = oh[lane * 2 + 1];
    int lbl = -1;
    if (a.x > 0.5f) lbl = lane * 8 + 0;
    if (a.y > 0.5f) lbl = lane * 8 + 1;
    if (a.z > 0.5f) lbl = lane * 8 + 2;
    if (a.w > 0.5f) lbl = lane * 8 + 3;
    if (b.x > 0.5f) lbl = lane * 8 + 4;
    if (b.y > 0.5f) lbl = lane * 8 + 5;
    if (b.z > 0.5f) lbl = lane * 8 + 6;
    if (b.w > 0.5f) lbl = lane * 8 + 7;
    #pragma unroll
    for (int off = 32; off > 0; off >>= 1)
        lbl = max(lbl, __shfl_xor(lbl, off));

    if (lane == 0) {
        label[row] = lbl;
        atomicAdd(&cnt[lbl], 1.0f);
    }
    // scatter this row of x0 (wave-coalesced; avg M/C=8 colliders per cell)
    float2 xv = reinterpret_cast<const float2*>(x0 + (size_t)row * D)[lane];
    atomicAdd(&sumx[lbl * D + lane * 2 + 0], xv.x);
    atomicAdd(&sumx[lbl * D + lane * 2 + 1], xv.y);
}

// ---- kernel 2: {new_centers row b} + {L1-distance tile (mb,cb)} ----
// grid = 512 blocks x 256 threads, 32 KB LDS. NO fences, NO finalize:
// d_pos / loss_part are plain stores; k_fin reduces after dispatch boundary.
__global__ __launch_bounds__(256) void k_dist(
    const float* __restrict__ x0, const float* __restrict__ centers,
    const int* __restrict__ label,
    const float* __restrict__ cnt, const float* __restrict__ sumx,
    float* __restrict__ d_pos, float* __restrict__ loss_part,
    float* __restrict__ out_nc)
{
    __shared__ float xs[64 * 64];    // 16 KB
    __shared__ float cs[64 * 64];    // 16 KB

    int tid = threadIdx.x;
    int b   = blockIdx.x;

    // ===== prologue: new_centers for class b (cnt/sumx are L2-hot) =====
    if (tid < D) {
        float n   = cnt[b];
        float s   = sumx[b * D + tid];
        float ctr = centers[b * D + tid];
        out_nc[b * D + tid] = ctr - ALPHA * (n * ctr - s) / (n + 1.0f);
    }

    // ===== L1-distance tile: swizzled staging (R5-proven) =====
    int mb = b & 63;            // m tile
    int cb = b >> 6;            // c chunk
    int m0 = mb * 64, c0 = cb * 64;
    int tx = tid & 15;          // -> 4 c rows
    int ty = tid >> 4;          // -> 4 m rows
    int xk = ty & 7;            // read-swizzle key for x rows
    int ck = tx & 7;            // read-swizzle key for c rows

    float acc[4][4];
    #pragma unroll
    for (int i = 0; i < 4; i++)
        #pragma unroll
        for (int j = 0; j < 4; j++) acc[i][j] = 0.f;

    for (int dc = 0; dc < 2; ++dc) {
        int d0 = dc * 64;
        __syncthreads();   // protect LDS from previous iteration's readers
        #pragma unroll
        for (int kk = 0; kk < 4; ++kk) {
            int Q   = kk * 256 + tid;                // physical quad 0..1023
            int row = Q >> 4;                        // 0..63
            int q   = (Q & 15) ^ ((row >> 2) & 7);   // logical quad (pre-swizzle
            float4 vx = *reinterpret_cast<const float4*>(   // the GLOBAL addr)
                x0      + (size_t)(m0 + row) * D + d0 + q * 4);
            float4 vc = *reinterpret_cast<const float4*>(
                centers + (size_t)(c0 + row) * D + d0 + q * 4);
            *reinterpret_cast<float4*>(xs + Q * 4) = vx;   // linear: no conflict
            *reinterpret_cast<float4*>(cs + Q * 4) = vc;
        }
        __syncthreads();

        #pragma unroll 4
        for (int q = 0; q < 16; ++q) {
            int xo = (q ^ xk) << 2;
            int co = (q ^ ck) << 2;
            float4 xa[4], ca[4];
            #pragma unroll
            for (int i = 0; i < 4; ++i)
                xa[i] = *reinterpret_cast<const float4*>(xs + (ty * 4 + i) * 64 + xo);
            #pragma unroll
            for (int j = 0; j < 4; ++j)
                ca[j] = *reinterpret_cast<const float4*>(cs + (tx * 4 + j) * 64 + co);
            #pragma unroll
            for (int i = 0; i < 4; ++i)
                #pragma unroll
                for (int j = 0; j < 4; ++j) {
                    acc[i][j] += fabsf(xa[i].x - ca[j].x);   // v_sub+v_add(|mod|)
                    acc[i][j] += fabsf(xa[i].y - ca[j].y);
                    acc[i][j] += fabsf(xa[i].z - ca[j].z);
                    acc[i][j] += fabsf(xa[i].w - ca[j].w);
                }
        }
    }

    // ===== epilogue: d_pos (unique owner) + per-chunk exp-sum partials =====
    int lbls[4];
    #pragma unroll
    for (int i = 0; i < 4; i++) lbls[i] = label[m0 + ty * 4 + i];

    #pragma unroll
    for (int i = 0; i < 4; i++) {
        float ps = 0.f;
        #pragma unroll
        for (int j = 0; j < 4; j++) {
            int cg = c0 + tx * 4 + j;
            float dist = acc[i][j];
            if (cg == lbls[i]) {
                d_pos[m0 + ty * 4 + i] = dist;        // unique writer per m
            } else {
                ps += __expf(-dist);
            }
        }
        #pragma unroll
        for (int off = 8; off > 0; off >>= 1)         // 16-lane tx group
            ps += __shfl_xor(ps, off);
        if (tx == 0)
            loss_part[(size_t)(m0 + ty * 4 + i) * 8 + cb] = ps;
    }
}

// ---- kernel 3: loss[m] = d_pos[m] + log1p(sum of 8 chunk partials) ----
__global__ __launch_bounds__(256) void k_fin(
    const float* __restrict__ d_pos, const float* __restrict__ loss_part,
    float* __restrict__ loss_out)
{
    int m = blockIdx.x * 256 + threadIdx.x;
    if (m >= M) return;
    const float4* p = reinterpret_cast<const float4*>(loss_part + (size_t)m * 8);
    float4 a = p[0], b = p[1];
    float s = (a.x + a.y) + (a.z + a.w) + (b.x + b.y) + (b.z + b.w);
    loss_out[m] = d_pos[m] + log1pf(s);
}

extern "C" void kernel_launch(void* const* d_in, const int* in_sizes, int n_in,
                              void* d_out, int out_size, void* d_ws, size_t ws_size,
                              hipStream_t stream)
{
    const float* x0      = (const float*)d_in[0];   // (M, D)
    const float* onehot  = (const float*)d_in[1];   // (M, C)
    const float* centers = (const float*)d_in[2];   // (C, D)
    float* out = (float*)d_out;                     // [0..M) loss, [M..) new_centers

    char* ws = (char*)d_ws;
    float* cnt       = (float*)(ws + WS_CNT);
    float* sumx      = (float*)(ws + WS_SUMX);
    int*   label     = (int*)  (ws + WS_LABEL);
    float* d_pos     = (float*)(ws + WS_DPOS);
    float* loss_part = (float*)(ws + WS_LPART);

    k_zero <<<(ZERO_WORDS + 255) / 256, 256, 0, stream>>>((unsigned int*)d_ws);
    k_label<<<M / 4,   256, 0, stream>>>(onehot, x0, label, cnt, sumx);
    k_dist <<<512,     256, 0, stream>>>(x0, centers, label, cnt, sumx,
                                         d_pos, loss_part, out + M);
    k_fin  <<<M / 256, 256, 0, stream>>>(d_pos, loss_part, out);
}